// Round 1
// baseline (300.515 us; speedup 1.0000x reference)
//
#include <hip/hip_runtime.h>
#include <hip/hip_bf16.h>

typedef __bf16  bf16x8 __attribute__((ext_vector_type(8)));
typedef float   floatx4 __attribute__((ext_vector_type(4)));

#define GLOB_AS __attribute__((address_space(1)))
#define LDS_AS  __attribute__((address_space(3)))

__device__ __forceinline__ void async_copy16(void* lds, const void* g) {
  __builtin_amdgcn_global_load_lds((const GLOB_AS void*)g, (LDS_AS void*)lds, 16, 0, 0);
}

// ---------------- prep kernels ----------------

// prototypes (1024,256,3,3) fp32 -> wT bf16 [p][(kh*3+kw)*256 + c], + ps_sq[p]
__global__ __launch_bounds__(256) void prep_w(const float* __restrict__ w,
                                              __hip_bfloat16* __restrict__ wT,
                                              float* __restrict__ ps) {
  const int p = blockIdx.x;
  const int c = threadIdx.x;
  const float* src = w + ((long)p * 256 + c) * 9;
  float s = 0.f;
#pragma unroll
  for (int t = 0; t < 9; ++t) {
    float v = src[t];
    s += v * v;
    wT[(long)p * 2304 + t * 256 + c] = __float2bfloat16(v);
  }
  __shared__ float red[256];
  red[c] = s;
  __syncthreads();
  for (int off = 128; off > 0; off >>= 1) {
    if (c < off) red[c] += red[c + off];
    __syncthreads();
  }
  if (c == 0) ps[p] = red[0];
}

// x (32,256,28,28) fp32 -> xT bf16 NHWC (32,28,28,256)
__global__ __launch_bounds__(256) void prep_x(const float* __restrict__ x,
                                              __hip_bfloat16* __restrict__ xT) {
  const int bh = blockIdx.x;     // 32*28
  const int b = bh / 28, h = bh - b * 28;
  const int c = threadIdx.x;
  __shared__ __hip_bfloat16 tile[28][256];
  const float* src = x + (((long)b * 256 + c) * 28 + h) * 28;
#pragma unroll
  for (int w = 0; w < 28; ++w) tile[w][c] = __float2bfloat16(src[w]);
  __syncthreads();
  __hip_bfloat16* dst = xT + ((long)(b * 28 + h) * 28) * 256 + c;
#pragma unroll
  for (int w = 0; w < 28; ++w) dst[w * 256] = tile[w][c];
}

// sq[b][h][w] = sum_c x^2   (exact fp32)
__global__ __launch_bounds__(64) void prep_sq(const float* __restrict__ x,
                                              float* __restrict__ sq) {
  const int bh = blockIdx.x;     // 32*28
  const int b = bh / 28, h = bh - b * 28;
  const int w = threadIdx.x;
  if (w >= 28) return;
  const float* src = x + (long)b * 256 * 784 + h * 28 + w;
  float s = 0.f;
  for (int c = 0; c < 256; ++c) {
    float v = src[(long)c * 784];
    s += v * v;
  }
  sq[bh * 28 + w] = s;
}

// xs_box[pix] = 3x3 box sum of sq
__global__ __launch_bounds__(128) void prep_box(const float* __restrict__ sq,
                                                float* __restrict__ xs) {
  const int pix = blockIdx.x * 128 + threadIdx.x;   // 169*128 = 21632 exactly
  const int b = pix / 676;
  const int rem = pix - b * 676;
  const int oh = rem / 26, ow = rem - oh * 26;
  const float* s = sq + (b * 28 + oh) * 28 + ow;
  float v = 0.f;
#pragma unroll
  for (int kh = 0; kh < 3; ++kh)
#pragma unroll
    for (int kw = 0; kw < 3; ++kw) v += s[kh * 28 + kw];
  xs[pix] = v;
}

// ---------------- main implicit-GEMM kernel ----------------
// C[p][pix] = sum_k A[p][k] * B[pix][k]   (both tiles stored [row][32k] in LDS)
// M = 1024 protos (8 tiles), N = 21632 pixels (169 tiles), K = 2304 (72 steps)
__global__ __launch_bounds__(256) void l2_main(
    const __hip_bfloat16* __restrict__ wT,   // [1024][2304]
    const __hip_bfloat16* __restrict__ xT,   // [32][28][28][256]
    const float* __restrict__ ps_sq,         // [1024]
    const float* __restrict__ xs_box,        // [21632]
    float* __restrict__ out)                 // [32][1024][676]
{
  __shared__ __hip_bfloat16 As[128 * 32];
  __shared__ __hip_bfloat16 Bs[128 * 32];

  const int tid = threadIdx.x;
  const int wv = tid >> 6;
  const int lane = tid & 63;
  const int n0 = blockIdx.x * 128;   // pixel tile
  const int p0 = blockIdx.y * 128;   // proto tile

  // staging: 512 x 16B per tile; thread does 2 A-loads + 2 B-loads per K-step
  const int fA0 = tid, fA1 = tid + 256;
  const int rA0 = fA0 >> 2, rA1 = fA1 >> 2;       // row in tile (0..127)
  const int q0 = (fA0 & 3) * 8, q1 = (fA1 & 3) * 8;  // element offset in 32-wide row

  const long aOff0 = (long)(p0 + rA0) * 2304 + q0;
  const long aOff1 = (long)(p0 + rA1) * 2304 + q1;

  const int pix0 = n0 + rA0, pix1 = n0 + rA1;
  const int b0 = pix0 / 676, e0 = pix0 - b0 * 676;
  const int b1 = pix1 / 676, e1 = pix1 - b1 * 676;
  const int oh0 = e0 / 26, ow0 = e0 - oh0 * 26;
  const int oh1 = e1 / 26, ow1 = e1 - oh1 * 26;
  const long bOff0 = (long)((b0 * 28 + oh0) * 28 + ow0) * 256 + q0;
  const long bOff1 = (long)((b1 * 28 + oh1) * 28 + ow1) * 256 + q1;

  // wave-uniform LDS dest bases (bytes); lane adds l*16 in HW
  const int dst0 = wv * 1024;
  const int dst1 = 4096 + wv * 1024;
  char* ldsA = (char*)As;
  char* ldsB = (char*)Bs;

  floatx4 acc[4][4];
#pragma unroll
  for (int i = 0; i < 4; ++i)
#pragma unroll
    for (int j = 0; j < 4; ++j) acc[i][j] = (floatx4){0.f, 0.f, 0.f, 0.f};

  const int wm = wv >> 1, wn = wv & 1;
  // fragment read bases (elements): row = sub + (lane&15), kcol = (lane>>4)*8
  const int aFragBase = (wm * 64 + (lane & 15)) * 32 + (lane >> 4) * 8;
  const int bFragBase = (wn * 64 + (lane & 15)) * 32 + (lane >> 4) * 8;

  for (int ks = 0; ks < 72; ++ks) {
    const int k0 = ks * 32;
    const int slice = ks >> 3;          // 0..8 : (kh,kw)
    const int c0 = (ks & 7) * 32;       // channel offset within slice
    const int kh = slice / 3;
    const int kw = slice - kh * 3;
    const long so = (long)((kh * 28 + kw) * 256 + c0);

    async_copy16(ldsA + dst0, wT + aOff0 + k0);
    async_copy16(ldsA + dst1, wT + aOff1 + k0);
    async_copy16(ldsB + dst0, xT + bOff0 + so);
    async_copy16(ldsB + dst1, xT + bOff1 + so);
    __syncthreads();

    bf16x8 af[4], bfr[4];
#pragma unroll
    for (int i = 0; i < 4; ++i)
      af[i] = *(const bf16x8*)(As + aFragBase + i * 16 * 32);
#pragma unroll
    for (int j = 0; j < 4; ++j)
      bfr[j] = *(const bf16x8*)(Bs + bFragBase + j * 16 * 32);

#pragma unroll
    for (int i = 0; i < 4; ++i)
#pragma unroll
      for (int j = 0; j < 4; ++j)
        acc[i][j] = __builtin_amdgcn_mfma_f32_16x16x32_bf16(af[i], bfr[j], acc[i][j], 0, 0, 0);
    __syncthreads();
  }

  // epilogue: d = sqrt(max(xs + ps - 2*acc, 1e-14))
  const int colBase = n0 + wn * 64 + (lane & 15);   // pixel
  const int rowBase = p0 + wm * 64 + (lane >> 4) * 4; // proto

  float psv[4][4];
#pragma unroll
  for (int i = 0; i < 4; ++i)
#pragma unroll
    for (int r = 0; r < 4; ++r) psv[i][r] = ps_sq[rowBase + i * 16 + r];

#pragma unroll
  for (int j = 0; j < 4; ++j) {
    const int pix = colBase + j * 16;
    const int b = pix / 676;
    const int pb = pix - b * 676;
    const float xs = xs_box[pix];
    float* op = out + (long)b * 676 * 1024 + pb;
#pragma unroll
    for (int i = 0; i < 4; ++i) {
      const int p = rowBase + i * 16;
#pragma unroll
      for (int r = 0; r < 4; ++r) {
        float d2 = xs + psv[i][r] - 2.0f * acc[i][j][r];
        op[(long)(p + r) * 676] = sqrtf(fmaxf(d2, 1e-14f));
      }
    }
  }
}

// ---------------- launcher ----------------

extern "C" void kernel_launch(void* const* d_in, const int* in_sizes, int n_in,
                              void* d_out, int out_size, void* d_ws, size_t ws_size,
                              hipStream_t stream) {
  const float* x = (const float*)d_in[0];        // (32,256,28,28)
  const float* w = (const float*)d_in[1];        // (1024,256,3,3)
  float* out = (float*)d_out;                    // (32,1024,26,26)

  char* ws = (char*)d_ws;
  __hip_bfloat16* wT = (__hip_bfloat16*)ws;                       // 4,718,592 B
  __hip_bfloat16* xT = (__hip_bfloat16*)(ws + 4718592);           // 12,845,056 B
  float* ps = (float*)(ws + 17563648);                            // 4,096 B
  float* sq = (float*)(ws + 17567744);                            // 100,352 B
  float* xs = (float*)(ws + 17668096);                            // 86,528 B
  // total ws use: 17,754,624 B

  prep_w<<<1024, 256, 0, stream>>>(w, wT, ps);
  prep_x<<<32 * 28, 256, 0, stream>>>(x, xT);
  prep_sq<<<32 * 28, 64, 0, stream>>>(x, sq);
  prep_box<<<169, 128, 0, stream>>>(sq, xs);

  dim3 grid(169, 8);
  l2_main<<<grid, 256, 0, stream>>>(wT, xT, ps, xs, out);
}

// Round 2
// 248.701 us; speedup vs baseline: 1.2083x; 1.2083x over previous
//
#include <hip/hip_runtime.h>
#include <hip/hip_bf16.h>

typedef __bf16  bf16x8 __attribute__((ext_vector_type(8)));
typedef float   floatx4 __attribute__((ext_vector_type(4)));

#define GLOB_AS __attribute__((address_space(1)))
#define LDS_AS  __attribute__((address_space(3)))

__device__ __forceinline__ void async_copy16(void* l, const void* g) {
  __builtin_amdgcn_global_load_lds((const GLOB_AS void*)g, (LDS_AS void*)l, 16, 0, 0);
}

#define BAR()       __builtin_amdgcn_s_barrier()
#define WAIT_VM(N)  asm volatile("s_waitcnt vmcnt(" #N ")" ::: "memory")
#define WAIT_LGKM() asm volatile("s_waitcnt lgkmcnt(0)" ::: "memory")

// ---------------- fused prep kernel ----------------
// blocks 0..895     : x (32,256,28,28) fp32 -> xT bf16 NHWC
// blocks 896..1919  : prototypes -> wT bf16 [p][(kh*3+kw)*256+c], ps_sq[p]
// blocks 1920..2815 : sq[b][h][w] = sum_c x^2 (exact fp32)
__global__ __launch_bounds__(256) void prep_all(const float* __restrict__ x,
                                                const float* __restrict__ w,
                                                __hip_bfloat16* __restrict__ xT,
                                                __hip_bfloat16* __restrict__ wT,
                                                float* __restrict__ ps,
                                                float* __restrict__ sq) {
  __shared__ __hip_bfloat16 tile[28][256];
  __shared__ float redw[256];
  __shared__ float reds[256];

  const int bid = blockIdx.x;
  const int tid = threadIdx.x;

  if (bid < 896) {
    const int b = bid / 28, h = bid - b * 28;
    const float* src = x + (((long)b * 256 + tid) * 28 + h) * 28;
#pragma unroll
    for (int ww = 0; ww < 28; ++ww) tile[ww][tid] = __float2bfloat16(src[ww]);
    __syncthreads();
    __hip_bfloat16* dst = xT + ((long)(b * 28 + h) * 28) * 256 + tid;
#pragma unroll
    for (int ww = 0; ww < 28; ++ww) dst[ww * 256] = tile[ww][tid];
  } else if (bid < 1920) {
    const int p = bid - 896;
    const float* src = w + ((long)p * 256 + tid) * 9;
    float s = 0.f;
#pragma unroll
    for (int t = 0; t < 9; ++t) {
      float v = src[t];
      s += v * v;
      wT[(long)p * 2304 + t * 256 + tid] = __float2bfloat16(v);
    }
    redw[tid] = s;
    __syncthreads();
    for (int off = 128; off > 0; off >>= 1) {
      if (tid < off) redw[tid] += redw[tid + off];
      __syncthreads();
    }
    if (tid == 0) ps[p] = redw[0];
  } else {
    const int bh = bid - 1920;
    const int b = bh / 28, h = bh - b * 28;
    const int ww = tid & 31, grp = tid >> 5;   // 8 groups x 32 channels
    float s = 0.f;
    if (ww < 28) {
      const float* src = x + (((long)b * 256 + grp * 32) * 28 + h) * 28 + ww;
      for (int cc = 0; cc < 32; ++cc) {
        float v = src[(long)cc * 784];
        s += v * v;
      }
    }
    reds[tid] = s;
    __syncthreads();
    if (tid < 32) {
      float v = 0.f;
#pragma unroll
      for (int g = 0; g < 8; ++g) v += reds[g * 32 + tid];
      if (tid < 28) sq[bh * 28 + tid] = v;
    }
  }
}

// ---------------- main kernel: ring-3 counted-vmcnt implicit GEMM ----------------
// C[p][pix] = sum_k wT[p][k] * xTpatch[pix][k]; BM=256 BN=128 BK=64, 8 waves.
// LDS stage (48 KB): A[256][64] bf16 (32 KB) | B[128][64] bf16 (16 KB), XOR-swizzled.
__global__ __launch_bounds__(512, 1) void l2_main(
    const __hip_bfloat16* __restrict__ wT,   // [1024][2304]
    const __hip_bfloat16* __restrict__ xT,   // [32][28][28][256]
    const float* __restrict__ ps_sq,         // [1024]
    const float* __restrict__ sq,            // [32][28][28]
    float* __restrict__ out)                 // [32][1024][676]
{
  __shared__ __attribute__((aligned(16))) char lds[3 * 49152];

  const int tid = threadIdx.x;
  const int wv = tid >> 6;
  const int lane = tid & 63;

  // T1: bijective XCD-chunk swizzle (676 = 4*85 + 4*84)
  const int bid = blockIdx.x;
  const int xcd = bid & 7, loc = bid >> 3;
  const int wg = (xcd < 4 ? xcd * 85 : 340 + (xcd - 4) * 84) + loc;
  const int py = wg / 169;
  const int nx = wg - py * 169;
  const int p0 = py << 8;      // proto base
  const int n0 = nx << 7;      // pixel base

  // ---- staging addresses (T2: inverse-swizzled global source, linear LDS dest) ----
  const int l8 = lane >> 3;                       // row-within-8 (= row&7 of staged row)
  const int kbyte = ((lane & 7) << 4) ^ (l8 << 4);
  const int ke = kbyte >> 1;                      // element offset 0..63 (mult of 8)

  const __hip_bfloat16* aSrc0 = wT + (long)(p0 +   0 + wv * 8 + l8) * 2304 + ke;
  const __hip_bfloat16* aSrc1 = wT + (long)(p0 +  64 + wv * 8 + l8) * 2304 + ke;
  const __hip_bfloat16* aSrc2 = wT + (long)(p0 + 128 + wv * 8 + l8) * 2304 + ke;
  const __hip_bfloat16* aSrc3 = wT + (long)(p0 + 192 + wv * 8 + l8) * 2304 + ke;

  const __hip_bfloat16 *bSrc0, *bSrc1;
  {
    int pix = n0 + wv * 8 + l8;
    int b = pix / 676, e = pix - b * 676;
    int oh = e / 26, ow = e - oh * 26;
    bSrc0 = xT + (long)((b * 28 + oh) * 28 + ow) * 256 + ke;
    pix += 64;
    b = pix / 676; e = pix - b * 676; oh = e / 26; ow = e - oh * 26;
    bSrc1 = xT + (long)((b * 28 + oh) * 28 + ow) * 256 + ke;
  }

  const int aD0 = wv * 1024, aD1 = 8192 + wv * 1024;
  const int aD2 = 16384 + wv * 1024, aD3 = 24576 + wv * 1024;
  const int bD0 = 32768 + wv * 1024, bD1 = 40960 + wv * 1024;

  // per-K-tile B slice offset: k = kt*64 -> (kh,kw) slice + channel chunk
  auto kOffB = [](int kt) {
    int s = kt >> 2;
    int sh = s / 3, sw2 = s - 3 * sh;
    return (sh * 28 + sw2) * 256 + ((kt & 3) << 6);
  };
  auto stageH0 = [&](int kt, int sb) {
    const long ka = (long)kt << 6;
    const int kb2 = kOffB(kt);
    async_copy16(lds + sb + aD0, aSrc0 + ka);
    async_copy16(lds + sb + aD1, aSrc1 + ka);
    async_copy16(lds + sb + bD0, bSrc0 + kb2);
  };
  auto stageH1 = [&](int kt, int sb) {
    const long ka = (long)kt << 6;
    const int kb2 = kOffB(kt);
    async_copy16(lds + sb + aD2, aSrc2 + ka);
    async_copy16(lds + sb + aD3, aSrc3 + ka);
    async_copy16(lds + sb + bD1, bSrc1 + kb2);
  };

  // ---- fragment read addressing (swizzled) ----
  const int ln15 = lane & 15;
  const int swz = (lane & 7) << 4;                    // row&7 of frag row = lane&7
  const int k0 = ((lane >> 4) << 4) ^ swz;            // k-half 0
  const int k1 = (64 + ((lane >> 4) << 4)) ^ swz;     // k-half 1
  const int aRowB = ((wv >> 1) * 64 + ln15) * 128;
  const int bRowB = 32768 + ((wv & 1) * 64 + ln15) * 128;

  floatx4 acc[4][4];
#pragma unroll
  for (int i = 0; i < 4; ++i)
#pragma unroll
    for (int j = 0; j < 4; ++j) acc[i][j] = (floatx4){0.f, 0.f, 0.f, 0.f};

  // prologue: tiles 0 and 1 in flight (12 loads), confirm tile 0
  stageH0(0, 0);      stageH1(0, 0);
  stageH0(1, 49152);  stageH1(1, 49152);
  WAIT_VM(6);
  BAR();

  int curS = 0, stgS = 2 * 49152;
  for (int t = 0; t < 36; ++t) {
    // ---- phase 0 (k 0..31) ----
    {
      bf16x8 af[4], bq[4];
#pragma unroll
      for (int i = 0; i < 4; ++i)
        af[i] = *(const bf16x8*)(lds + curS + aRowB + i * 2048 + k0);
#pragma unroll
      for (int j = 0; j < 4; ++j)
        bq[j] = *(const bf16x8*)(lds + curS + bRowB + j * 2048 + k0);
      if (t < 34) stageH0(t + 2, stgS);
      BAR();
      WAIT_LGKM();
      __builtin_amdgcn_s_setprio(1);
#pragma unroll
      for (int i = 0; i < 4; ++i)
#pragma unroll
        for (int j = 0; j < 4; ++j)
          acc[i][j] = __builtin_amdgcn_mfma_f32_16x16x32_bf16(af[i], bq[j], acc[i][j], 0, 0, 0);
      __builtin_amdgcn_s_setprio(0);
      BAR();
    }
    // ---- phase 1 (k 32..63) ----
    {
      bf16x8 af[4], bq[4];
#pragma unroll
      for (int i = 0; i < 4; ++i)
        af[i] = *(const bf16x8*)(lds + curS + aRowB + i * 2048 + k1);
#pragma unroll
      for (int j = 0; j < 4; ++j)
        bq[j] = *(const bf16x8*)(lds + curS + bRowB + j * 2048 + k1);
      if (t < 34) stageH1(t + 2, stgS);
      if (t < 34) { WAIT_VM(6); } else if (t == 34) { WAIT_VM(0); }
      BAR();
      WAIT_LGKM();
      __builtin_amdgcn_s_setprio(1);
#pragma unroll
      for (int i = 0; i < 4; ++i)
#pragma unroll
        for (int j = 0; j < 4; ++j)
          acc[i][j] = __builtin_amdgcn_mfma_f32_16x16x32_bf16(af[i], bq[j], acc[i][j], 0, 0, 0);
      __builtin_amdgcn_s_setprio(0);
      BAR();
    }
    curS += 49152; if (curS == 147456) curS = 0;
    stgS += 49152; if (stgS == 147456) stgS = 0;
  }

  // ---- epilogue: d = sqrt(max(xs_box + ps - 2*acc, 1e-14)), box folded in ----
  const int pixBase = n0 + (wv & 1) * 64 + ln15;
  const int rowBase = p0 + (wv >> 1) * 64 + ((lane >> 4) << 2);

  float psv[4][4];
#pragma unroll
  for (int i = 0; i < 4; ++i)
#pragma unroll
    for (int rr = 0; rr < 4; ++rr) psv[i][rr] = ps_sq[rowBase + i * 16 + rr];

#pragma unroll
  for (int j = 0; j < 4; ++j) {
    const int pix = pixBase + j * 16;
    const int b = pix / 676;
    const int pb = pix - b * 676;
    const int oh = pb / 26, ow = pb - oh * 26;
    const float* sp = sq + (b * 28 + oh) * 28 + ow;
    float xs = 0.f;
#pragma unroll
    for (int kh = 0; kh < 3; ++kh)
#pragma unroll
      for (int kw = 0; kw < 3; ++kw) xs += sp[kh * 28 + kw];
    float* op = out + (long)b * 676 * 1024 + pb;
#pragma unroll
    for (int i = 0; i < 4; ++i)
#pragma unroll
      for (int rr = 0; rr < 4; ++rr) {
        float d2 = xs + psv[i][rr] - 2.0f * acc[i][j][rr];
        op[(long)(rowBase + i * 16 + rr) * 676] = sqrtf(fmaxf(d2, 1e-14f));
      }
  }
}

// ---------------- launcher ----------------

extern "C" void kernel_launch(void* const* d_in, const int* in_sizes, int n_in,
                              void* d_out, int out_size, void* d_ws, size_t ws_size,
                              hipStream_t stream) {
  const float* x = (const float*)d_in[0];        // (32,256,28,28)
  const float* w = (const float*)d_in[1];        // (1024,256,3,3)
  float* out = (float*)d_out;                    // (32,1024,26,26)

  char* ws = (char*)d_ws;
  __hip_bfloat16* wT = (__hip_bfloat16*)ws;                       // 4,718,592 B
  __hip_bfloat16* xT = (__hip_bfloat16*)(ws + 4718592);           // 12,845,056 B
  float* ps = (float*)(ws + 17563648);                            // 4,096 B
  float* sq = (float*)(ws + 17567744);                            // 100,352 B

  prep_all<<<2816, 256, 0, stream>>>(x, w, xT, wT, ps, sq);
  l2_main<<<676, 512, 0, stream>>>(wT, xT, ps, sq, out);
}